// Round 7
// baseline (362.906 us; speedup 1.0000x reference)
//
#include <hip/hip_runtime.h>
#include <math.h>

typedef __attribute__((ext_vector_type(8))) short  bf16x8;
typedef __attribute__((ext_vector_type(4))) float  f32x4;
typedef __attribute__((ext_vector_type(8))) ushort u16x8;
typedef __attribute__((ext_vector_type(4))) ushort u16x4;

#define SEQ   2048
#define CDIM  2048
#define NHEAD 16
#define DHEAD 128
#define SCALE 0.02209708691207961f
#define LOG2E 1.4426950408889634f

__device__ __forceinline__ ushort f2bf(float f) {
    uint u = __float_as_uint(f);
    u += 0x7FFFu + ((u >> 16) & 1u);
    return (ushort)(u >> 16);
}
__device__ __forceinline__ float bf2f(ushort h) {
    return __uint_as_float(((uint)h) << 16);
}

#define GLOAD16(gsrc, ldst)                                                  \
    __builtin_amdgcn_global_load_lds(                                        \
        (const __attribute__((address_space(1))) void*)(gsrc),               \
        (__attribute__((address_space(3))) void*)(ldst), 16, 0, 0)

// ------------------------------------------ f32 -> bf16, 5 matrices fused
__global__ __launch_bounds__(256) void f2bf5_kernel(
    const float* __restrict__ s0, const float* __restrict__ s1,
    const float* __restrict__ s2, const float* __restrict__ s3,
    const float* __restrict__ s4,
    ushort* __restrict__ d0, ushort* __restrict__ d1,
    ushort* __restrict__ d2, ushort* __restrict__ d3,
    ushort* __restrict__ d4)
{
    const int z = blockIdx.y;
    const float* src = z == 0 ? s0 : z == 1 ? s1 : z == 2 ? s2 : z == 3 ? s3 : s4;
    ushort*      dst = z == 0 ? d0 : z == 1 ? d1 : z == 2 ? d2 : z == 3 ? d3 : d4;
    const int i = blockIdx.x * 256 + threadIdx.x;
    const float4 a = ((const float4*)src)[i * 2];
    const float4 b = ((const float4*)src)[i * 2 + 1];
    u16x8 o;
    o[0] = f2bf(a.x); o[1] = f2bf(a.y); o[2] = f2bf(a.z); o[3] = f2bf(a.w);
    o[4] = f2bf(b.x); o[5] = f2bf(b.y); o[6] = f2bf(b.z); o[7] = f2bf(b.w);
    *(u16x8*)&dst[(size_t)i * 8] = o;
}

// ------------------------------------------------------- bf16 MFMA NT GEMM
// BK=64: 32 MFMA per barrier-pair, half the barrier/drain count of BK=32.
// C[m,n] = sum_k A[m,k]*B[n,k] + bias[n]; out fp32 (final projection)
__global__ __launch_bounds__(256) void gemm_nt_mfma_f32(const ushort* __restrict__ A,
                                                        const ushort* __restrict__ B,
                                                        const float* __restrict__ bias,
                                                        float* __restrict__ outp)
{
    __shared__ ushort As[128 * 64];
    __shared__ ushort Bs[128 * 64];
    const int tid  = threadIdx.x;
    const int lane = tid & 63, wid = tid >> 6;
    const int wr = wid >> 1, wc = wid & 1;
    const int l4 = lane >> 4, l15 = lane & 15;
    const int m0 = blockIdx.y * 128, n0 = blockIdx.x * 128;

    f32x4 acc[4][4];
    #pragma unroll
    for (int i = 0; i < 4; ++i)
        #pragma unroll
        for (int j = 0; j < 4; ++j) acc[i][j] = 0.f;

    const int srow = lane >> 3;           // 0..7
    const int scol = (lane & 7) * 8;      // 0..56

    for (int k0 = 0; k0 < CDIM; k0 += 64) {
        __syncthreads();
        #pragma unroll
        for (int i2 = 0; i2 < 4; ++i2) {
            GLOAD16(&A[(size_t)(m0 + wid * 32 + i2 * 8 + srow) * CDIM + k0 + scol],
                    (char*)As + wid * 4096 + i2 * 1024);
            GLOAD16(&B[(size_t)(n0 + wid * 32 + i2 * 8 + srow) * CDIM + k0 + scol],
                    (char*)Bs + wid * 4096 + i2 * 1024);
        }
        __syncthreads();

        #pragma unroll
        for (int sk = 0; sk < 2; ++sk) {
            bf16x8 af[4], bfr[4];
            #pragma unroll
            for (int f = 0; f < 4; ++f) {
                af[f]  = *(const bf16x8*)&As[(wr * 64 + f * 16 + l15) * 64 + sk * 32 + l4 * 8];
                bfr[f] = *(const bf16x8*)&Bs[(wc * 64 + f * 16 + l15) * 64 + sk * 32 + l4 * 8];
            }
            #pragma unroll
            for (int i = 0; i < 4; ++i)
                #pragma unroll
                for (int j = 0; j < 4; ++j)
                    acc[i][j] = __builtin_amdgcn_mfma_f32_16x16x32_bf16(af[i], bfr[j], acc[i][j], 0, 0, 0);
        }
    }

    float bn[4];
    #pragma unroll
    for (int j = 0; j < 4; ++j) bn[j] = bias[n0 + wc * 64 + j * 16 + l15];

    #pragma unroll
    for (int i = 0; i < 4; ++i)
        #pragma unroll
        for (int j = 0; j < 4; ++j) {
            const int n = n0 + wc * 64 + j * 16 + l15;
            #pragma unroll
            for (int r = 0; r < 4; ++r) {
                const int m = m0 + wr * 64 + i * 16 + l4 * 4 + r;
                outp[(size_t)m * CDIM + n] = acc[i][j][r] + bn[j];
            }
        }
}

// Fused QKV GEMM + RoPE epilogue (q,k). BK=64. blockIdx.z selects output.
// z==0 -> q (bf16 row-major, rope), z==1 -> k (bf16 row-major, rope),
// z==2 -> vT (bf16 TRANSPOSED: vT[n][m], leading dim SEQ, no rope).
__global__ __launch_bounds__(256) void gemm_qkv(const ushort* __restrict__ A,
                                                const ushort* __restrict__ W0,
                                                const ushort* __restrict__ W1,
                                                const ushort* __restrict__ W2,
                                                const float* __restrict__ b0,
                                                const float* __restrict__ b1,
                                                const float* __restrict__ b2,
                                                const float* __restrict__ cosT,
                                                const float* __restrict__ sinT,
                                                ushort* __restrict__ o0,
                                                ushort* __restrict__ o1,
                                                ushort* __restrict__ o2)
{
    __shared__ ushort As[128 * 64];
    __shared__ ushort Bs[128 * 64];
    const int z = blockIdx.z;
    const ushort* B    = z == 0 ? W0 : z == 1 ? W1 : W2;
    const float*  bias = z == 0 ? b0 : z == 1 ? b1 : b2;

    const int tid  = threadIdx.x;
    const int lane = tid & 63, wid = tid >> 6;
    const int wr = wid >> 1, wc = wid & 1;
    const int l4 = lane >> 4, l15 = lane & 15;
    const int m0 = blockIdx.y * 128, n0 = blockIdx.x * 128;

    f32x4 acc[4][4];
    #pragma unroll
    for (int i = 0; i < 4; ++i)
        #pragma unroll
        for (int j = 0; j < 4; ++j) acc[i][j] = 0.f;

    const int srow = lane >> 3;
    const int scol = (lane & 7) * 8;

    for (int k0 = 0; k0 < CDIM; k0 += 64) {
        __syncthreads();
        #pragma unroll
        for (int i2 = 0; i2 < 4; ++i2) {
            GLOAD16(&A[(size_t)(m0 + wid * 32 + i2 * 8 + srow) * CDIM + k0 + scol],
                    (char*)As + wid * 4096 + i2 * 1024);
            GLOAD16(&B[(size_t)(n0 + wid * 32 + i2 * 8 + srow) * CDIM + k0 + scol],
                    (char*)Bs + wid * 4096 + i2 * 1024);
        }
        __syncthreads();

        #pragma unroll
        for (int sk = 0; sk < 2; ++sk) {
            bf16x8 af[4], bfr[4];
            #pragma unroll
            for (int f = 0; f < 4; ++f) {
                af[f]  = *(const bf16x8*)&As[(wr * 64 + f * 16 + l15) * 64 + sk * 32 + l4 * 8];
                bfr[f] = *(const bf16x8*)&Bs[(wc * 64 + f * 16 + l15) * 64 + sk * 32 + l4 * 8];
            }
            #pragma unroll
            for (int i = 0; i < 4; ++i)
                #pragma unroll
                for (int j = 0; j < 4; ++j)
                    acc[i][j] = __builtin_amdgcn_mfma_f32_16x16x32_bf16(af[i], bfr[j], acc[i][j], 0, 0, 0);
        }
    }

    float bn[4];
    #pragma unroll
    for (int j = 0; j < 4; ++j) bn[j] = bias[n0 + wc * 64 + j * 16 + l15];

    if (z == 2) {
        // transposed write: vT[n][m], 4 consecutive m per lane -> 8B stores
        #pragma unroll
        for (int i = 0; i < 4; ++i)
            #pragma unroll
            for (int j = 0; j < 4; ++j) {
                const int n = n0 + wc * 64 + j * 16 + l15;
                const int mb = m0 + wr * 64 + i * 16 + l4 * 4;
                u16x4 pk;
                #pragma unroll
                for (int r = 0; r < 4; ++r) pk[r] = f2bf(acc[i][j][r] + bn[j]);
                *(u16x4*)&o2[(size_t)n * SEQ + mb] = pk;
            }
    } else {
        // RoPE fused: pair (d, d^1) lives in adjacent lanes (n bit0 == l15 bit0)
        ushort* outp = z == 0 ? o0 : o1;
        #pragma unroll
        for (int i = 0; i < 4; ++i)
            #pragma unroll
            for (int j = 0; j < 4; ++j) {
                const int n  = n0 + wc * 64 + j * 16 + l15;
                const int fi = (n & 127) >> 1;
                const bool odd = (n & 1) != 0;
                #pragma unroll
                for (int r = 0; r < 4; ++r) {
                    const int m = m0 + wr * 64 + i * 16 + l4 * 4 + r;
                    const float val     = acc[i][j][r] + bn[j];
                    const float partner = __shfl_xor(val, 1);
                    const float c = cosT[m * 64 + fi];
                    const float s = sinT[m * 64 + fi];
                    const float res = odd ? (partner * s + val * c)
                                          : (val * c - partner * s);
                    outp[(size_t)m * CDIM + n] = f2bf(res);
                }
            }
    }
}

// ------------------------------------------------------ MFMA flash attention
// (round-5 structure: 4 waves 2x2, S via LDS round-trip, 4-lane/row softmax,
//  T14 issue-early K/V staging, V pre-transposed vT[d][t].)
__global__ __launch_bounds__(256) void flash_attn_mfma(const ushort* __restrict__ qb,
                                                       const ushort* __restrict__ kb,
                                                       const ushort* __restrict__ vT,
                                                       ushort* __restrict__ ao)
{
    __shared__ ushort Ks[64 * 136];    // row stride 272 B
    __shared__ ushort VTs[128 * 72];   // [d][kv], row stride 144 B
    __shared__ float  S_lds[64 * 68];
    __shared__ ushort Ps[64 * 72];
    __shared__ float  rowM[64], rowL[64], rowF[64];

    const int tid  = threadIdx.x;
    const int lane = tid & 63, wid = tid >> 6;
    const int wr = wid >> 1, wc = wid & 1;
    const int l4 = lane >> 4, l15 = lane & 15;
    const int h = blockIdx.y;
    const int qt = gridDim.x - 1 - blockIdx.x;   // longest blocks dispatch first
    const int q0 = qt * 64;

    if (tid < 64) { rowM[tid] = -INFINITY; rowL[tid] = 0.f; }

    // Q fragments in registers, reused across all K-tiles
    bf16x8 qf[2][4];
    #pragma unroll
    for (int fm = 0; fm < 2; ++fm)
        #pragma unroll
        for (int ks = 0; ks < 4; ++ks) {
            const int row = q0 + wr * 32 + fm * 16 + l15;
            const int col = h * DHEAD + ks * 32 + l4 * 8;
            qf[fm][ks] = *(const bf16x8*)&qb[(size_t)row * CDIM + col];
        }

    f32x4 acc_o[2][4];
    #pragma unroll
    for (int fm = 0; fm < 2; ++fm)
        #pragma unroll
        for (int fn = 0; fn < 4; ++fn) acc_o[fm][fn] = 0.f;

    // T14: issue-early K/V staging registers
    const int rK = tid >> 4,  cK = (tid & 15) * 8;
    const int rV = tid >> 3,  cV = (tid & 7) * 8;
    u16x8 kreg[4], vreg[4];

    // prologue: issue loads for kt=0
    #pragma unroll
    for (int i2 = 0; i2 < 4; ++i2)
        kreg[i2] = *(const u16x8*)&kb[(size_t)(rK + i2 * 16) * CDIM + h * DHEAD + cK];
    #pragma unroll
    for (int i2 = 0; i2 < 4; ++i2)
        vreg[i2] = *(const u16x8*)&vT[(size_t)(h * DHEAD + rV + i2 * 32) * SEQ + cV];

    for (int kt = 0; kt <= qt; ++kt) {
        __syncthreads();   // previous PV done before overwriting LDS

        // ---- write staged K/V regs -> LDS
        #pragma unroll
        for (int i2 = 0; i2 < 4; ++i2)
            *(u16x8*)&Ks[(rK + i2 * 16) * 136 + cK] = kreg[i2];
        #pragma unroll
        for (int i2 = 0; i2 < 4; ++i2)
            *(u16x8*)&VTs[(rV + i2 * 32) * 72 + cV] = vreg[i2];
        __syncthreads();

        // ---- S = Q K^T  (each wave: 32x32 of the 64x64 tile)
        f32x4 sacc[2][2];
        #pragma unroll
        for (int fm = 0; fm < 2; ++fm)
            #pragma unroll
            for (int fn = 0; fn < 2; ++fn) sacc[fm][fn] = 0.f;
        #pragma unroll
        for (int ks = 0; ks < 4; ++ks) {
            bf16x8 kf[2];
            #pragma unroll
            for (int fn = 0; fn < 2; ++fn)
                kf[fn] = *(const bf16x8*)&Ks[(wc * 32 + fn * 16 + l15) * 136 + ks * 32 + l4 * 8];
            #pragma unroll
            for (int fm = 0; fm < 2; ++fm)
                #pragma unroll
                for (int fn = 0; fn < 2; ++fn)
                    sacc[fm][fn] = __builtin_amdgcn_mfma_f32_16x16x32_bf16(qf[fm][ks], kf[fn], sacc[fm][fn], 0, 0, 0);
        }

        // ---- T14: issue next tile's K/V loads (fly under softmax+PV)
        if (kt < qt) {
            #pragma unroll
            for (int i2 = 0; i2 < 4; ++i2)
                kreg[i2] = *(const u16x8*)&kb[(size_t)((kt + 1) * 64 + rK + i2 * 16) * CDIM + h * DHEAD + cK];
            #pragma unroll
            for (int i2 = 0; i2 < 4; ++i2)
                vreg[i2] = *(const u16x8*)&vT[(size_t)(h * DHEAD + rV + i2 * 32) * SEQ + (kt + 1) * 64 + cV];
        }

        #pragma unroll
        for (int fm = 0; fm < 2; ++fm)
            #pragma unroll
            for (int fn = 0; fn < 2; ++fn)
                #pragma unroll
                for (int r = 0; r < 4; ++r) {
                    const int srow = wr * 32 + fm * 16 + l4 * 4 + r;
                    const int scol = wc * 32 + fn * 16 + l15;
                    float sv = sacc[fm][fn][r] * SCALE;
                    if (kt == qt && scol > srow) sv = -INFINITY;
                    S_lds[srow * 68 + scol] = sv;
                }
        __syncthreads();

        // ---- online softmax: 4 lanes per row
        {
            const int srow = tid >> 2;
            const int c0   = (tid & 3) * 16;
            float vals[16];
            #pragma unroll
            for (int c = 0; c < 16; ++c) vals[c] = S_lds[srow * 68 + c0 + c];
            float mt = vals[0];
            #pragma unroll
            for (int c = 1; c < 16; ++c) mt = fmaxf(mt, vals[c]);
            mt = fmaxf(mt, __shfl_xor(mt, 1));
            mt = fmaxf(mt, __shfl_xor(mt, 2));
            const float mold = rowM[srow];
            const float mnew = fmaxf(mold, mt);
            float sum = 0.f;
            ushort pb[16];
            #pragma unroll
            for (int c = 0; c < 16; ++c) {
                const float p = exp2f((vals[c] - mnew) * LOG2E);
                sum += p;
                pb[c] = f2bf(p);
            }
            sum += __shfl_xor(sum, 1);
            sum += __shfl_xor(sum, 2);
            u16x8 w0, w1;
            #pragma unroll
            for (int c = 0; c < 8; ++c) { w0[c] = pb[c]; w1[c] = pb[c + 8]; }
            *(u16x8*)&Ps[srow * 72 + c0]     = w0;
            *(u16x8*)&Ps[srow * 72 + c0 + 8] = w1;
            if ((tid & 3) == 0) {
                const float fac = exp2f((mold - mnew) * LOG2E);
                rowF[srow] = fac;
                rowL[srow] = rowL[srow] * fac + sum;
                rowM[srow] = mnew;
            }
        }
        __syncthreads();

        // ---- rescale O, then O += P V
        float frv[2][4];
        #pragma unroll
        for (int fm = 0; fm < 2; ++fm)
            #pragma unroll
            for (int r = 0; r < 4; ++r)
                frv[fm][r] = rowF[wr * 32 + fm * 16 + l4 * 4 + r];
        #pragma unroll
        for (int fm = 0; fm < 2; ++fm)
            #pragma unroll
            for (int fn = 0; fn < 4; ++fn)
                #pragma unroll
                for (int r = 0; r < 4; ++r) acc_o[fm][fn][r] *= frv[fm][r];

        #pragma unroll
        for (int ks = 0; ks < 2; ++ks) {
            bf16x8 pa[2];
            #pragma unroll
            for (int fm = 0; fm < 2; ++fm)
                pa[fm] = *(const bf16x8*)&Ps[(wr * 32 + fm * 16 + l15) * 72 + ks * 32 + l4 * 8];
            #pragma unroll
            for (int fn = 0; fn < 4; ++fn) {
                bf16x8 vf = *(const bf16x8*)&VTs[(wc * 64 + fn * 16 + l15) * 72 + ks * 32 + l4 * 8];
                #pragma unroll
                for (int fm = 0; fm < 2; ++fm)
                    acc_o[fm][fn] = __builtin_amdgcn_mfma_f32_16x16x32_bf16(pa[fm], vf, acc_o[fm][fn], 0, 0, 0);
            }
        }
    }

    // ---- epilogue: O /= rowL, store bf16
    #pragma unroll
    for (int fm = 0; fm < 2; ++fm)
        #pragma unroll
        for (int r = 0; r < 4; ++r) {
            const int lrow = wr * 32 + fm * 16 + l4 * 4 + r;
            const float invl = 1.f / rowL[lrow];
            #pragma unroll
            for (int fn = 0; fn < 4; ++fn) {
                const int gcol = h * DHEAD + wc * 64 + fn * 16 + l15;
                ao[(size_t)(q0 + lrow) * CDIM + gcol] = f2bf(acc_o[fm][fn][r] * invl);
            }
        }
}

extern "C" void kernel_launch(void* const* d_in, const int* in_sizes, int n_in,
                              void* d_out, int out_size, void* d_ws, size_t ws_size,
                              hipStream_t stream) {
    const float* x    = (const float*)d_in[0];
    const float* wq   = (const float*)d_in[1];
    const float* bq   = (const float*)d_in[2];
    const float* wk   = (const float*)d_in[3];
    const float* bk   = (const float*)d_in[4];
    const float* wv   = (const float*)d_in[5];
    const float* bv   = (const float*)d_in[6];
    const float* wp   = (const float*)d_in[7];
    const float* bp   = (const float*)d_in[8];
    const float* cosT = (const float*)d_in[9];
    const float* sinT = (const float*)d_in[10];

    const size_t mat = (size_t)SEQ * CDIM;   // 4M elements
    ushort* xb  = (ushort*)d_ws;             // also reused as attn output
    ushort* w0  = xb  + mat;
    ushort* w1  = w0  + mat;
    ushort* w2  = w1  + mat;
    ushort* w3  = w2  + mat;
    ushort* qbb = w3  + mat;
    ushort* kbb = qbb + mat;
    ushort* vTb = kbb + mat;
    ushort* aob = xb;            // x (bf16) dead after gemm_qkv

    const int n8 = (int)(mat / 8);

    f2bf5_kernel<<<dim3(n8 / 256, 5), 256, 0, stream>>>(x, wq, wk, wv, wp,
                                                        xb, w0, w1, w2, w3);

    gemm_qkv<<<dim3(16, 16, 3), 256, 0, stream>>>(xb, w0, w1, w2, bq, bk, bv,
                                                  cosT, sinT, qbb, kbb, vTb);

    flash_attn_mfma<<<dim3(SEQ / 64, NHEAD), 256, 0, stream>>>(qbb, kbb, vTb, aob);

    gemm_nt_mfma_f32<<<dim3(16, 16), 256, 0, stream>>>(aob, w3, bp, (float*)d_out);

    (void)in_sizes; (void)n_in; (void)out_size; (void)ws_size;
}

// Round 8
// 351.216 us; speedup vs baseline: 1.0333x; 1.0333x over previous
//
#include <hip/hip_runtime.h>
#include <math.h>

typedef __attribute__((ext_vector_type(8))) short  bf16x8;
typedef __attribute__((ext_vector_type(4))) float  f32x4;
typedef __attribute__((ext_vector_type(8))) ushort u16x8;
typedef __attribute__((ext_vector_type(4))) ushort u16x4;

#define SEQ   2048
#define CDIM  2048
#define NHEAD 16
#define DHEAD 128
#define SCALE 0.02209708691207961f
#define LOG2E 1.4426950408889634f

__device__ __forceinline__ ushort f2bf(float f) {
    uint u = __float_as_uint(f);
    u += 0x7FFFu + ((u >> 16) & 1u);
    return (ushort)(u >> 16);
}
__device__ __forceinline__ float bf2f(ushort h) {
    return __uint_as_float(((uint)h) << 16);
}

#define GLOAD16(gsrc, ldst)                                                  \
    __builtin_amdgcn_global_load_lds(                                        \
        (const __attribute__((address_space(1))) void*)(gsrc),               \
        (__attribute__((address_space(3))) void*)(ldst), 16, 0, 0)

// ------------------------------------------ f32 -> bf16, 5 matrices fused
__global__ __launch_bounds__(256) void f2bf5_kernel(
    const float* __restrict__ s0, const float* __restrict__ s1,
    const float* __restrict__ s2, const float* __restrict__ s3,
    const float* __restrict__ s4,
    ushort* __restrict__ d0, ushort* __restrict__ d1,
    ushort* __restrict__ d2, ushort* __restrict__ d3,
    ushort* __restrict__ d4)
{
    const int z = blockIdx.y;
    const float* src = z == 0 ? s0 : z == 1 ? s1 : z == 2 ? s2 : z == 3 ? s3 : s4;
    ushort*      dst = z == 0 ? d0 : z == 1 ? d1 : z == 2 ? d2 : z == 3 ? d3 : d4;
    const int i = blockIdx.x * 256 + threadIdx.x;
    const float4 a = ((const float4*)src)[i * 2];
    const float4 b = ((const float4*)src)[i * 2 + 1];
    u16x8 o;
    o[0] = f2bf(a.x); o[1] = f2bf(a.y); o[2] = f2bf(a.z); o[3] = f2bf(a.w);
    o[4] = f2bf(b.x); o[5] = f2bf(b.y); o[6] = f2bf(b.z); o[7] = f2bf(b.w);
    *(u16x8*)&dst[(size_t)i * 8] = o;
}

// ------------------------------------------------------- bf16 MFMA NT GEMM
// BK=32 (conflict-free), double-buffered LDS: STAGE(next) issued before
// compute(cur); ONE barrier per K-substep (its vmcnt/lgkm drain covers both
// the staging completion and the frag-read completion).
// C[m,n] = sum_k A[m,k]*B[n,k] + bias[n]; out fp32 (final projection)
__global__ __launch_bounds__(256) void gemm_nt_mfma_f32(const ushort* __restrict__ A,
                                                        const ushort* __restrict__ B,
                                                        const float* __restrict__ bias,
                                                        float* __restrict__ outp)
{
    __shared__ ushort As[2][128 * 32];
    __shared__ ushort Bs[2][128 * 32];
    const int tid  = threadIdx.x;
    const int lane = tid & 63, wid = tid >> 6;
    const int wr = wid >> 1, wc = wid & 1;
    const int l4 = lane >> 4, l15 = lane & 15;
    const int m0 = blockIdx.y * 128, n0 = blockIdx.x * 128;

    f32x4 acc[4][4];
    #pragma unroll
    for (int i = 0; i < 4; ++i)
        #pragma unroll
        for (int j = 0; j < 4; ++j) acc[i][j] = 0.f;

    const int srow = wid * 32 + (lane >> 2);
    const int scol = (lane & 3) * 8;

#define STAGE_P(b, k0)                                                                        \
    GLOAD16(&A[(size_t)(m0 + srow)      * CDIM + (k0) + scol], (char*)&As[b][0] + wid * 2048);        \
    GLOAD16(&A[(size_t)(m0 + srow + 16) * CDIM + (k0) + scol], (char*)&As[b][0] + wid * 2048 + 1024); \
    GLOAD16(&B[(size_t)(n0 + srow)      * CDIM + (k0) + scol], (char*)&Bs[b][0] + wid * 2048);        \
    GLOAD16(&B[(size_t)(n0 + srow + 16) * CDIM + (k0) + scol], (char*)&Bs[b][0] + wid * 2048 + 1024);

#define COMPUTE_P(b)                                                                          \
    {                                                                                         \
        bf16x8 af[4], bfr[4];                                                                 \
        _Pragma("unroll")                                                                     \
        for (int f = 0; f < 4; ++f) {                                                         \
            af[f]  = *(const bf16x8*)&As[b][(wr * 64 + f * 16 + l15) * 32 + l4 * 8];          \
            bfr[f] = *(const bf16x8*)&Bs[b][(wc * 64 + f * 16 + l15) * 32 + l4 * 8];          \
        }                                                                                     \
        _Pragma("unroll")                                                                     \
        for (int i = 0; i < 4; ++i)                                                           \
            _Pragma("unroll")                                                                 \
            for (int j = 0; j < 4; ++j)                                                       \
                acc[i][j] = __builtin_amdgcn_mfma_f32_16x16x32_bf16(af[i], bfr[j], acc[i][j], 0, 0, 0); \
    }

    STAGE_P(0, 0);
    __syncthreads();
    for (int k0 = 0; k0 < CDIM; k0 += 64) {
        STAGE_P(1, k0 + 32);          // prefetch next substep (always valid)
        COMPUTE_P(0);
        __syncthreads();
        if (k0 + 64 < CDIM) { STAGE_P(0, k0 + 64); }
        COMPUTE_P(1);
        __syncthreads();
    }
#undef STAGE_P
#undef COMPUTE_P

    float bn[4];
    #pragma unroll
    for (int j = 0; j < 4; ++j) bn[j] = bias[n0 + wc * 64 + j * 16 + l15];

    #pragma unroll
    for (int i = 0; i < 4; ++i)
        #pragma unroll
        for (int j = 0; j < 4; ++j) {
            const int n = n0 + wc * 64 + j * 16 + l15;
            #pragma unroll
            for (int r = 0; r < 4; ++r) {
                const int m = m0 + wr * 64 + i * 16 + l4 * 4 + r;
                outp[(size_t)m * CDIM + n] = acc[i][j][r] + bn[j];
            }
        }
}

// Fused QKV GEMM + RoPE epilogue (q,k). BK=32, double-buffered prefetch.
// z==0 -> q (bf16 row-major, rope), z==1 -> k (bf16 row-major, rope),
// z==2 -> vT (bf16 TRANSPOSED: vT[n][m], leading dim SEQ, no rope).
__global__ __launch_bounds__(256) void gemm_qkv(const ushort* __restrict__ A,
                                                const ushort* __restrict__ W0,
                                                const ushort* __restrict__ W1,
                                                const ushort* __restrict__ W2,
                                                const float* __restrict__ b0,
                                                const float* __restrict__ b1,
                                                const float* __restrict__ b2,
                                                const float* __restrict__ cosT,
                                                const float* __restrict__ sinT,
                                                ushort* __restrict__ o0,
                                                ushort* __restrict__ o1,
                                                ushort* __restrict__ o2)
{
    __shared__ ushort As[2][128 * 32];
    __shared__ ushort Bs[2][128 * 32];
    const int z = blockIdx.z;
    const ushort* B    = z == 0 ? W0 : z == 1 ? W1 : W2;
    const float*  bias = z == 0 ? b0 : z == 1 ? b1 : b2;

    const int tid  = threadIdx.x;
    const int lane = tid & 63, wid = tid >> 6;
    const int wr = wid >> 1, wc = wid & 1;
    const int l4 = lane >> 4, l15 = lane & 15;
    const int m0 = blockIdx.y * 128, n0 = blockIdx.x * 128;

    f32x4 acc[4][4];
    #pragma unroll
    for (int i = 0; i < 4; ++i)
        #pragma unroll
        for (int j = 0; j < 4; ++j) acc[i][j] = 0.f;

    const int srow = wid * 32 + (lane >> 2);
    const int scol = (lane & 3) * 8;

#define STAGE_P(b, k0)                                                                        \
    GLOAD16(&A[(size_t)(m0 + srow)      * CDIM + (k0) + scol], (char*)&As[b][0] + wid * 2048);        \
    GLOAD16(&A[(size_t)(m0 + srow + 16) * CDIM + (k0) + scol], (char*)&As[b][0] + wid * 2048 + 1024); \
    GLOAD16(&B[(size_t)(n0 + srow)      * CDIM + (k0) + scol], (char*)&Bs[b][0] + wid * 2048);        \
    GLOAD16(&B[(size_t)(n0 + srow + 16) * CDIM + (k0) + scol], (char*)&Bs[b][0] + wid * 2048 + 1024);

#define COMPUTE_P(b)                                                                          \
    {                                                                                         \
        bf16x8 af[4], bfr[4];                                                                 \
        _Pragma("unroll")                                                                     \
        for (int f = 0; f < 4; ++f) {                                                         \
            af[f]  = *(const bf16x8*)&As[b][(wr * 64 + f * 16 + l15) * 32 + l4 * 8];          \
            bfr[f] = *(const bf16x8*)&Bs[b][(wc * 64 + f * 16 + l15) * 32 + l4 * 8];          \
        }                                                                                     \
        _Pragma("unroll")                                                                     \
        for (int i = 0; i < 4; ++i)                                                           \
            _Pragma("unroll")                                                                 \
            for (int j = 0; j < 4; ++j)                                                       \
                acc[i][j] = __builtin_amdgcn_mfma_f32_16x16x32_bf16(af[i], bfr[j], acc[i][j], 0, 0, 0); \
    }

    STAGE_P(0, 0);
    __syncthreads();
    for (int k0 = 0; k0 < CDIM; k0 += 64) {
        STAGE_P(1, k0 + 32);
        COMPUTE_P(0);
        __syncthreads();
        if (k0 + 64 < CDIM) { STAGE_P(0, k0 + 64); }
        COMPUTE_P(1);
        __syncthreads();
    }
#undef STAGE_P
#undef COMPUTE_P

    float bn[4];
    #pragma unroll
    for (int j = 0; j < 4; ++j) bn[j] = bias[n0 + wc * 64 + j * 16 + l15];

    if (z == 2) {
        // transposed write: vT[n][m], 4 consecutive m per lane -> 8B stores
        #pragma unroll
        for (int i = 0; i < 4; ++i)
            #pragma unroll
            for (int j = 0; j < 4; ++j) {
                const int n = n0 + wc * 64 + j * 16 + l15;
                const int mb = m0 + wr * 64 + i * 16 + l4 * 4;
                u16x4 pk;
                #pragma unroll
                for (int r = 0; r < 4; ++r) pk[r] = f2bf(acc[i][j][r] + bn[j]);
                *(u16x4*)&o2[(size_t)n * SEQ + mb] = pk;
            }
    } else {
        // RoPE fused: pair (d, d^1) lives in adjacent lanes (n bit0 == l15 bit0)
        ushort* outp = z == 0 ? o0 : o1;
        #pragma unroll
        for (int i = 0; i < 4; ++i)
            #pragma unroll
            for (int j = 0; j < 4; ++j) {
                const int n  = n0 + wc * 64 + j * 16 + l15;
                const int fi = (n & 127) >> 1;
                const bool odd = (n & 1) != 0;
                #pragma unroll
                for (int r = 0; r < 4; ++r) {
                    const int m = m0 + wr * 64 + i * 16 + l4 * 4 + r;
                    const float val     = acc[i][j][r] + bn[j];
                    const float partner = __shfl_xor(val, 1);
                    const float c = cosT[m * 64 + fi];
                    const float s = sinT[m * 64 + fi];
                    const float res = odd ? (partner * s + val * c)
                                          : (val * c - partner * s);
                    outp[(size_t)m * CDIM + n] = f2bf(res);
                }
            }
    }
}

// ------------------------------------------------------ MFMA flash attention
// (round-5 structure: 4 waves 2x2, S via LDS round-trip, 4-lane/row softmax,
//  T14 issue-early K/V staging, V pre-transposed vT[d][t].)
__global__ __launch_bounds__(256) void flash_attn_mfma(const ushort* __restrict__ qb,
                                                       const ushort* __restrict__ kb,
                                                       const ushort* __restrict__ vT,
                                                       ushort* __restrict__ ao)
{
    __shared__ ushort Ks[64 * 136];    // row stride 272 B
    __shared__ ushort VTs[128 * 72];   // [d][kv], row stride 144 B
    __shared__ float  S_lds[64 * 68];
    __shared__ ushort Ps[64 * 72];
    __shared__ float  rowM[64], rowL[64], rowF[64];

    const int tid  = threadIdx.x;
    const int lane = tid & 63, wid = tid >> 6;
    const int wr = wid >> 1, wc = wid & 1;
    const int l4 = lane >> 4, l15 = lane & 15;
    const int h = blockIdx.y;
    const int qt = gridDim.x - 1 - blockIdx.x;   // longest blocks dispatch first
    const int q0 = qt * 64;

    if (tid < 64) { rowM[tid] = -INFINITY; rowL[tid] = 0.f; }

    // Q fragments in registers, reused across all K-tiles
    bf16x8 qf[2][4];
    #pragma unroll
    for (int fm = 0; fm < 2; ++fm)
        #pragma unroll
        for (int ks = 0; ks < 4; ++ks) {
            const int row = q0 + wr * 32 + fm * 16 + l15;
            const int col = h * DHEAD + ks * 32 + l4 * 8;
            qf[fm][ks] = *(const bf16x8*)&qb[(size_t)row * CDIM + col];
        }

    f32x4 acc_o[2][4];
    #pragma unroll
    for (int fm = 0; fm < 2; ++fm)
        #pragma unroll
        for (int fn = 0; fn < 4; ++fn) acc_o[fm][fn] = 0.f;

    // T14: issue-early K/V staging registers
    const int rK = tid >> 4,  cK = (tid & 15) * 8;
    const int rV = tid >> 3,  cV = (tid & 7) * 8;
    u16x8 kreg[4], vreg[4];

    // prologue: issue loads for kt=0
    #pragma unroll
    for (int i2 = 0; i2 < 4; ++i2)
        kreg[i2] = *(const u16x8*)&kb[(size_t)(rK + i2 * 16) * CDIM + h * DHEAD + cK];
    #pragma unroll
    for (int i2 = 0; i2 < 4; ++i2)
        vreg[i2] = *(const u16x8*)&vT[(size_t)(h * DHEAD + rV + i2 * 32) * SEQ + cV];

    for (int kt = 0; kt <= qt; ++kt) {
        __syncthreads();   // previous PV done before overwriting LDS

        // ---- write staged K/V regs -> LDS
        #pragma unroll
        for (int i2 = 0; i2 < 4; ++i2)
            *(u16x8*)&Ks[(rK + i2 * 16) * 136 + cK] = kreg[i2];
        #pragma unroll
        for (int i2 = 0; i2 < 4; ++i2)
            *(u16x8*)&VTs[(rV + i2 * 32) * 72 + cV] = vreg[i2];
        __syncthreads();

        // ---- S = Q K^T  (each wave: 32x32 of the 64x64 tile)
        f32x4 sacc[2][2];
        #pragma unroll
        for (int fm = 0; fm < 2; ++fm)
            #pragma unroll
            for (int fn = 0; fn < 2; ++fn) sacc[fm][fn] = 0.f;
        #pragma unroll
        for (int ks = 0; ks < 4; ++ks) {
            bf16x8 kf[2];
            #pragma unroll
            for (int fn = 0; fn < 2; ++fn)
                kf[fn] = *(const bf16x8*)&Ks[(wc * 32 + fn * 16 + l15) * 136 + ks * 32 + l4 * 8];
            #pragma unroll
            for (int fm = 0; fm < 2; ++fm)
                #pragma unroll
                for (int fn = 0; fn < 2; ++fn)
                    sacc[fm][fn] = __builtin_amdgcn_mfma_f32_16x16x32_bf16(qf[fm][ks], kf[fn], sacc[fm][fn], 0, 0, 0);
        }

        // ---- T14: issue next tile's K/V loads (fly under softmax+PV)
        if (kt < qt) {
            #pragma unroll
            for (int i2 = 0; i2 < 4; ++i2)
                kreg[i2] = *(const u16x8*)&kb[(size_t)((kt + 1) * 64 + rK + i2 * 16) * CDIM + h * DHEAD + cK];
            #pragma unroll
            for (int i2 = 0; i2 < 4; ++i2)
                vreg[i2] = *(const u16x8*)&vT[(size_t)(h * DHEAD + rV + i2 * 32) * SEQ + (kt + 1) * 64 + cV];
        }

        #pragma unroll
        for (int fm = 0; fm < 2; ++fm)
            #pragma unroll
            for (int fn = 0; fn < 2; ++fn)
                #pragma unroll
                for (int r = 0; r < 4; ++r) {
                    const int srow = wr * 32 + fm * 16 + l4 * 4 + r;
                    const int scol = wc * 32 + fn * 16 + l15;
                    float sv = sacc[fm][fn][r] * SCALE;
                    if (kt == qt && scol > srow) sv = -INFINITY;
                    S_lds[srow * 68 + scol] = sv;
                }
        __syncthreads();

        // ---- online softmax: 4 lanes per row
        {
            const int srow = tid >> 2;
            const int c0   = (tid & 3) * 16;
            float vals[16];
            #pragma unroll
            for (int c = 0; c < 16; ++c) vals[c] = S_lds[srow * 68 + c0 + c];
            float mt = vals[0];
            #pragma unroll
            for (int c = 1; c < 16; ++c) mt = fmaxf(mt, vals[c]);
            mt = fmaxf(mt, __shfl_xor(mt, 1));
            mt = fmaxf(mt, __shfl_xor(mt, 2));
            const float mold = rowM[srow];
            const float mnew = fmaxf(mold, mt);
            float sum = 0.f;
            ushort pb[16];
            #pragma unroll
            for (int c = 0; c < 16; ++c) {
                const float p = exp2f((vals[c] - mnew) * LOG2E);
                sum += p;
                pb[c] = f2bf(p);
            }
            sum += __shfl_xor(sum, 1);
            sum += __shfl_xor(sum, 2);
            u16x8 w0, w1;
            #pragma unroll
            for (int c = 0; c < 8; ++c) { w0[c] = pb[c]; w1[c] = pb[c + 8]; }
            *(u16x8*)&Ps[srow * 72 + c0]     = w0;
            *(u16x8*)&Ps[srow * 72 + c0 + 8] = w1;
            if ((tid & 3) == 0) {
                const float fac = exp2f((mold - mnew) * LOG2E);
                rowF[srow] = fac;
                rowL[srow] = rowL[srow] * fac + sum;
                rowM[srow] = mnew;
            }
        }
        __syncthreads();

        // ---- rescale O, then O += P V
        float frv[2][4];
        #pragma unroll
        for (int fm = 0; fm < 2; ++fm)
            #pragma unroll
            for (int r = 0; r < 4; ++r)
                frv[fm][r] = rowF[wr * 32 + fm * 16 + l4 * 4 + r];
        #pragma unroll
        for (int fm = 0; fm < 2; ++fm)
            #pragma unroll
            for (int fn = 0; fn < 4; ++fn)
                #pragma unroll
                for (int r = 0; r < 4; ++r) acc_o[fm][fn][r] *= frv[fm][r];

        #pragma unroll
        for (int ks = 0; ks < 2; ++ks) {
            bf16x8 pa[2];
            #pragma unroll
            for (int fm = 0; fm < 2; ++fm)
                pa[fm] = *(const bf16x8*)&Ps[(wr * 32 + fm * 16 + l15) * 72 + ks * 32 + l4 * 8];
            #pragma unroll
            for (int fn = 0; fn < 4; ++fn) {
                bf16x8 vf = *(const bf16x8*)&VTs[(wc * 64 + fn * 16 + l15) * 72 + ks * 32 + l4 * 8];
                #pragma unroll
                for (int fm = 0; fm < 2; ++fm)
                    acc_o[fm][fn] = __builtin_amdgcn_mfma_f32_16x16x32_bf16(pa[fm], vf, acc_o[fm][fn], 0, 0, 0);
            }
        }
    }

    // ---- epilogue: O /= rowL, store bf16
    #pragma unroll
    for (int fm = 0; fm < 2; ++fm)
        #pragma unroll
        for (int r = 0; r < 4; ++r) {
            const int lrow = wr * 32 + fm * 16 + l4 * 4 + r;
            const float invl = 1.f / rowL[lrow];
            #pragma unroll
            for (int fn = 0; fn < 4; ++fn) {
                const int gcol = h * DHEAD + wc * 64 + fn * 16 + l15;
                ao[(size_t)(q0 + lrow) * CDIM + gcol] = f2bf(acc_o[fm][fn][r] * invl);
            }
        }
}

extern "C" void kernel_launch(void* const* d_in, const int* in_sizes, int n_in,
                              void* d_out, int out_size, void* d_ws, size_t ws_size,
                              hipStream_t stream) {
    const float* x    = (const float*)d_in[0];
    const float* wq   = (const float*)d_in[1];
    const float* bq   = (const float*)d_in[2];
    const float* wk   = (const float*)d_in[3];
    const float* bk   = (const float*)d_in[4];
    const float* wv   = (const float*)d_in[5];
    const float* bv   = (const float*)d_in[6];
    const float* wp   = (const float*)d_in[7];
    const float* bp   = (const float*)d_in[8];
    const float* cosT = (const float*)d_in[9];
    const float* sinT = (const float*)d_in[10];

    const size_t mat = (size_t)SEQ * CDIM;   // 4M elements
    ushort* xb  = (ushort*)d_ws;             // also reused as attn output
    ushort* w0  = xb  + mat;
    ushort* w1  = w0  + mat;
    ushort* w2  = w1  + mat;
    ushort* w3  = w2  + mat;
    ushort* qbb = w3  + mat;
    ushort* kbb = qbb + mat;
    ushort* vTb = kbb + mat;
    ushort* aob = xb;            // x (bf16) dead after gemm_qkv

    const int n8 = (int)(mat / 8);

    f2bf5_kernel<<<dim3(n8 / 256, 5), 256, 0, stream>>>(x, wq, wk, wv, wp,
                                                        xb, w0, w1, w2, w3);

    gemm_qkv<<<dim3(16, 16, 3), 256, 0, stream>>>(xb, w0, w1, w2, bq, bk, bv,
                                                  cosT, sinT, qbb, kbb, vTb);

    flash_attn_mfma<<<dim3(SEQ / 64, NHEAD), 256, 0, stream>>>(qbb, kbb, vTb, aob);

    gemm_nt_mfma_f32<<<dim3(16, 16), 256, 0, stream>>>(aob, w3, bp, (float*)d_out);

    (void)in_sizes; (void)n_in; (void)out_size; (void)ws_size;
}